// Round 4
// baseline (196.255 us; speedup 1.0000x reference)
//
#include <hip/hip_runtime.h>
#include <cmath>

#define NN 8192
#define DD 512
#define NSRC 8
#define SPLITS 16
#define BM 128
#define BN 128
#define BK 64
#define CPS (NN / SPLITS)     // 512 cols per split
#define CTILES (CPS / BN)     // 4 column tiles per block
#define COFF 100.0f           // fixed softmax offset (R3-validated: absmax 0)

typedef __bf16 bf16x8 __attribute__((ext_vector_type(8)));
typedef float  f32x16 __attribute__((ext_vector_type(16)));

__device__ __forceinline__ unsigned short f2bf(float f) {
    unsigned u = __float_as_uint(f);
    u += 0x7fffu + ((u >> 16) & 1u);
    return (unsigned short)(u >> 16);
}

// ---------------------------------------------------------------------------
// Kernel 0: fp32 -> bf16 cast (RNE). Block 0 zero-inits ps/Tsum/counts/out.
// ---------------------------------------------------------------------------
__global__ __launch_bounds__(256) void k_cast(
    const float* __restrict__ img, const float* __restrict__ txt,
    unsigned short* __restrict__ imgB, unsigned short* __restrict__ txtB,
    float* __restrict__ ps, float* __restrict__ Tsum,
    int* __restrict__ counts, float* __restrict__ out)
{
    if (blockIdx.x == 0) {
        const float4 z = {0.f, 0.f, 0.f, 0.f};
#pragma unroll
        for (int k = 0; k < 8; k++)     // ps: 8192 floats
            *(float4*)(ps + (k * 256 + threadIdx.x) * 4) = z;
#pragma unroll
        for (int k = 0; k < 4; k++)     // Tsum: 4096 floats
            *(float4*)(Tsum + (k * 256 + threadIdx.x) * 4) = z;
        if (threadIdx.x < NSRC) counts[threadIdx.x] = 0;
        if (threadIdx.x == 0) out[0] = 0.f;
    }
    const size_t gid = (size_t)blockIdx.x * 256 + threadIdx.x;
    const size_t half = (size_t)NN * DD / 8;   // chunks of 8 elements
    const float* src = (gid < half) ? img : txt;
    unsigned short* dst = (gid < half) ? imgB : txtB;
    const size_t off = ((gid < half) ? gid : gid - half) * 8;
    const float4 v0 = *(const float4*)(src + off);
    const float4 v1 = *(const float4*)(src + off + 4);
    union { unsigned short s[8]; uint4 v; } o;
    o.s[0] = f2bf(v0.x); o.s[1] = f2bf(v0.y); o.s[2] = f2bf(v0.z); o.s[3] = f2bf(v0.w);
    o.s[4] = f2bf(v1.x); o.s[5] = f2bf(v1.y); o.s[6] = f2bf(v1.z); o.s[7] = f2bf(v1.w);
    *(uint4*)(dst + off) = o.v;
}

// ---------------------------------------------------------------------------
// Kernel 1: per-source text sums + counts. REGISTER accumulation (R3 version
// was LDS-RMW latency-chained). Thread owns d-pair {2t, 2t+1}; lab is
// wave-uniform per row -> 8 cndmask+add per float, fully pipelined.
// 128 blocks x 64 rows; flush = 16 atomics/thread (128 per address).
// ---------------------------------------------------------------------------
__global__ __launch_bounds__(256) void k_src_sums(
    const float* __restrict__ txt, const int* __restrict__ labels,
    float* __restrict__ Tsum, int* __restrict__ counts)
{
    const int tid = threadIdx.x;
    const int d0 = 2 * tid;
    const int row0 = blockIdx.x * 64;
    float accx[NSRC], accy[NSRC];
#pragma unroll
    for (int s = 0; s < NSRC; s++) { accx[s] = 0.f; accy[s] = 0.f; }

    __shared__ int cacc[NSRC];
    if (tid < NSRC) cacc[tid] = 0;
    __syncthreads();
    if (tid < 64) atomicAdd(&cacc[labels[row0 + tid]], 1);

#pragma unroll 4
    for (int j = 0; j < 64; j++) {
        const int lab = labels[row0 + j];
        const float2 v = *(const float2*)(txt + (size_t)(row0 + j) * DD + d0);
#pragma unroll
        for (int s = 0; s < NSRC; s++) {
            accx[s] += (lab == s) ? v.x : 0.f;
            accy[s] += (lab == s) ? v.y : 0.f;
        }
    }
#pragma unroll
    for (int s = 0; s < NSRC; s++) {
        atomicAdd(&Tsum[s * DD + d0],     accx[s]);
        atomicAdd(&Tsum[s * DD + d0 + 1], accy[s]);
    }
    __syncthreads();
    if (tid < NSRC) atomicAdd(&counts[tid], cacc[tid]);
}

// ---------------------------------------------------------------------------
// Kernel 2: MFMA flash-lse, 32x32x16 bf16 (2382 TF ubench vs 2075 for 16x16).
// Block = 128 rows x 512-col split, BK=64; 4 waves; wave owns 32 rows
// (1 i-tile) x 128 cols (4 j-tiles). Fixed-offset expsum (no online max);
// per-row result atomically added to ps[row] (merge-free across splits).
// LDS: global_load_lds width=16, XOR k-chunk swizzle (R2/R3: 0 conflicts).
// C/D layout (m74/m101): col=lane&31, row=(reg&3)+8*(reg>>2)+4*(lane>>5).
// ---------------------------------------------------------------------------
__global__ __launch_bounds__(256, 4) void k_lse_mfma(
    const unsigned short* __restrict__ imgB, const unsigned short* __restrict__ txtB,
    const float* __restrict__ scale_p,
    float* __restrict__ ps)
{
    __shared__ uint4 lds[2048];            // A: [0,1024), B: [1024,2048) chunks
    const float scale = scale_p[0];
    const int tid  = threadIdx.x;
    const int lane = tid & 63;
    const int w    = tid >> 6;             // wave id
    const int split = blockIdx.x & (SPLITS - 1);
    const int by    = blockIdx.x / SPLITS;
    const int row0  = by * BM;
    const int colBase = split * CPS;
    const int lo = lane & 31;              // row/col within 32-tile
    const int hi = lane >> 5;              // k-half selector

    // staging geometry: thread stages physical chunk p = t*256 + tid
    int st_r[4], st_kc[4];
#pragma unroll
    for (int t = 0; t < 4; t++) {
        const int p = t * 256 + tid;
        st_r[t]  = p >> 3;
        st_kc[t] = (p & 7) ^ (st_r[t] & 7);
    }

    // fragment read bases (uint4 chunk indices)
    const int ar = w * 32 + lo;            // A row for this lane
    const int aIdx = ar * 8, aSw = ar & 7;
    int bIdx[4], bSw[4];
#pragma unroll
    for (int j = 0; j < 4; j++) {
        const int c = j * 32 + lo;         // B col for this lane
        bIdx[j] = 1024 + c * 8; bSw[j] = c & 7;
    }

    float s_run[16];
#pragma unroll
    for (int rg = 0; rg < 16; rg++) s_run[rg] = 0.f;

    for (int ct = 0; ct < CTILES; ct++) {
        const int col0 = colBase + ct * BN;
        f32x16 acc[4];
#pragma unroll
        for (int j = 0; j < 4; j++)
#pragma unroll
            for (int rg = 0; rg < 16; rg++) acc[j][rg] = 0.f;

        for (int kt = 0; kt < DD; kt += BK) {
            __syncthreads();               // previous tile's LDS reads done
#pragma unroll
            for (int t = 0; t < 4; t++) {  // stage A (128 rows x 64 k)
                const unsigned short* g =
                    imgB + (size_t)(row0 + st_r[t]) * DD + kt + (st_kc[t] << 3);
                __builtin_amdgcn_global_load_lds(
                    (const __attribute__((address_space(1))) void*)g,
                    (__attribute__((address_space(3))) void*)&lds[t * 256 + (w << 6)],
                    16, 0, 0);
            }
#pragma unroll
            for (int t = 0; t < 4; t++) {  // stage B (128 cols x 64 k)
                const unsigned short* g =
                    txtB + (size_t)(col0 + st_r[t]) * DD + kt + (st_kc[t] << 3);
                __builtin_amdgcn_global_load_lds(
                    (const __attribute__((address_space(1))) void*)g,
                    (__attribute__((address_space(3))) void*)&lds[1024 + t * 256 + (w << 6)],
                    16, 0, 0);
            }
            __syncthreads();               // drain global_load_lds
#pragma unroll
            for (int ks = 0; ks < 4; ks++) {   // 4 k-steps of 16
                const int kc = ks * 2 + hi;    // lane's k-chunk within BK
                const bf16x8 af = *reinterpret_cast<const bf16x8*>(
                    &lds[aIdx + (kc ^ aSw)]);
                bf16x8 bf[4];
#pragma unroll
                for (int j = 0; j < 4; j++)
                    bf[j] = *reinterpret_cast<const bf16x8*>(
                        &lds[bIdx[j] + (kc ^ bSw[j])]);
#pragma unroll
                for (int j = 0; j < 4; j++)
                    acc[j] = __builtin_amdgcn_mfma_f32_32x32x16_bf16(
                        af, bf[j], acc[j], 0, 0, 0);
            }
        }
        // epilogue: exp(logit - COFF), per-lane accumulation only
#pragma unroll
        for (int j = 0; j < 4; j++)
#pragma unroll
        for (int rg = 0; rg < 16; rg++)
            s_run[rg] += __expf(fmaf(acc[j][rg], scale, -COFF));
    }
    // reduce over the 32 col-lanes (xor offsets stay within the 32-group)
#pragma unroll
    for (int rg = 0; rg < 16; rg++) {
        float es = s_run[rg];
#pragma unroll
        for (int off = 16; off; off >>= 1) es += __shfl_xor(es, off);
        s_run[rg] = es;
    }
    if (lo == 0) {
#pragma unroll
        for (int rg = 0; rg < 16; rg++) {
            const int row = row0 + w * 32 + (rg & 3) + 8 * (rg >> 2) + 4 * hi;
            atomicAdd(&ps[row], s_run[rg]);
        }
    }
}

// ---------------------------------------------------------------------------
// Kernel 3: lse from ps, per-row fp32 dot products, loss reduce.
// 512 blocks x 4 waves x 4 rows.
// ---------------------------------------------------------------------------
__global__ __launch_bounds__(256) void k_finalize(
    const float* __restrict__ img, const float* __restrict__ txt,
    const int* __restrict__ labels, const float* __restrict__ scale_p,
    const float* __restrict__ Tsum, const int* __restrict__ counts,
    const float* __restrict__ ps,
    float* __restrict__ out)
{
    const float scale = scale_p[0];
    const int tid = threadIdx.x;
    const int lane = tid & 63;
    const int wave = tid >> 6;
    const int rowBase = blockIdx.x * 16 + wave * 4;
    float local = 0.f;
#pragma unroll
    for (int it = 0; it < 4; it++) {
        const int i = rowBase + it;
        const int lab = labels[i];
        float ds = 0.f, dt = 0.f;
        const float* ip = img + (size_t)i * DD;
        const float* tp = txt + (size_t)i * DD;
        const float* sp = Tsum + lab * DD;
#pragma unroll
        for (int k = lane; k < DD; k += 64) {
            const float a = ip[k];
            ds = fmaf(a, tp[k], ds);
            dt = fmaf(a, sp[k], dt);
        }
#pragma unroll
        for (int off = 32; off; off >>= 1) {
            ds += __shfl_xor(ds, off);
            dt += __shfl_xor(dt, off);
        }
        if (lane == 0) {
            const float lse = COFF + __logf(ps[i]);
            const int cnt = counts[lab] - 1;
            if (cnt > 0) {
                const float row_sum = scale * (dt - ds) - (float)cnt * lse;
                local += row_sum / (float)cnt;
            }
        }
    }
    __shared__ float red[4];
    if (lane == 0) red[wave] = local;
    __syncthreads();
    if (tid == 0) {
        const float t = red[0] + red[1] + red[2] + red[3];
        atomicAdd(out, -t / (float)NN);
    }
}

// ---------------------------------------------------------------------------
extern "C" void kernel_launch(void* const* d_in, const int* in_sizes, int n_in,
                              void* d_out, int out_size, void* d_ws, size_t ws_size,
                              hipStream_t stream)
{
    const float* img     = (const float*)d_in[0];
    const float* txt     = (const float*)d_in[1];
    const float* scale_p = (const float*)d_in[2];
    const int*   labels  = (const int*)d_in[3];
    float* out = (float*)d_out;

    char* ws = (char*)d_ws;
    float* ps    = (float*)(ws);                                  // 32 KB
    float* Tsum  = (float*)(ws + (size_t)NN * 4);                 // 16 KB
    int*   counts = (int*)(ws + (size_t)NN * 4 + NSRC * DD * 4);
    unsigned short* imgB = (unsigned short*)(ws + 2 * 1024 * 1024);       // 8 MB
    unsigned short* txtB = (unsigned short*)(ws + 10 * 1024 * 1024);      // 8 MB

    k_cast<<<(2 * NN * DD / 8) / 256, 256, 0, stream>>>(img, txt, imgB, txtB,
                                                        ps, Tsum, counts, out);
    k_src_sums<<<NN / 64, 256, 0, stream>>>(txt, labels, Tsum, counts);
    k_lse_mfma<<<(NN / BM) * SPLITS, 256, 0, stream>>>(imgB, txtB, scale_p, ps);
    k_finalize<<<NN / 16, 256, 0, stream>>>(img, txt, labels, scale_p,
                                            Tsum, counts, ps, out);
}

// Round 5
// 195.998 us; speedup vs baseline: 1.0013x; 1.0013x over previous
//
#include <hip/hip_runtime.h>
#include <cmath>

#define NN 8192
#define DD 512
#define NSRC 8
#define SPLITS 16
#define BM 128
#define BN 128
#define BK 64
#define CPS (NN / SPLITS)     // 512 cols per split
#define CTILES (CPS / BN)     // 4 column tiles per block
#define COFF 100.0f           // fixed softmax offset (R3/R4-validated: absmax 0)
#define SSBLK 128             // k_src_sums blocks (64 rows each)

typedef __bf16 bf16x8 __attribute__((ext_vector_type(8)));
typedef float  f32x16 __attribute__((ext_vector_type(16)));

__device__ __forceinline__ unsigned short f2bf(float f) {
    unsigned u = __float_as_uint(f);
    u += 0x7fffu + ((u >> 16) & 1u);
    return (unsigned short)(u >> 16);
}

// ---------------------------------------------------------------------------
// Kernel 0: fp32 -> bf16 cast (RNE). Block 0 zero-inits ps/counts/out.
// (Tsum is written non-atomically by k_src_reduce -> no init needed.)
// ---------------------------------------------------------------------------
__global__ __launch_bounds__(256) void k_cast(
    const float* __restrict__ img, const float* __restrict__ txt,
    unsigned short* __restrict__ imgB, unsigned short* __restrict__ txtB,
    float* __restrict__ ps, int* __restrict__ counts, float* __restrict__ out)
{
    if (blockIdx.x == 0) {
        const float4 z = {0.f, 0.f, 0.f, 0.f};
#pragma unroll
        for (int k = 0; k < 8; k++)     // ps: 8192 floats
            *(float4*)(ps + (k * 256 + threadIdx.x) * 4) = z;
        if (threadIdx.x < NSRC) counts[threadIdx.x] = 0;
        if (threadIdx.x == 0) out[0] = 0.f;
    }
    const size_t gid = (size_t)blockIdx.x * 256 + threadIdx.x;
    const size_t half = (size_t)NN * DD / 8;   // chunks of 8 elements
    const float* src = (gid < half) ? img : txt;
    unsigned short* dst = (gid < half) ? imgB : txtB;
    const size_t off = ((gid < half) ? gid : gid - half) * 8;
    const float4 v0 = *(const float4*)(src + off);
    const float4 v1 = *(const float4*)(src + off + 4);
    union { unsigned short s[8]; uint4 v; } o;
    o.s[0] = f2bf(v0.x); o.s[1] = f2bf(v0.y); o.s[2] = f2bf(v0.z); o.s[3] = f2bf(v0.w);
    o.s[4] = f2bf(v1.x); o.s[5] = f2bf(v1.y); o.s[6] = f2bf(v1.z); o.s[7] = f2bf(v1.w);
    *(uint4*)(dst + off) = o.v;
}

// ---------------------------------------------------------------------------
// Kernel 1a: per-source text sum PARTIALS. Register accumulation, then a
// plain coalesced float2 store of this block's 4096-entry partial — NO
// contended atomics (R3/R4's 524k atomic flush w/ 128-way contention was
// the suspected side-time hog). counts via 8 atomics/block (trivial).
// ---------------------------------------------------------------------------
__global__ __launch_bounds__(256) void k_src_sums(
    const float* __restrict__ txt, const int* __restrict__ labels,
    float* __restrict__ Tpart, int* __restrict__ counts)
{
    const int tid = threadIdx.x;
    const int d0 = 2 * tid;
    const int row0 = blockIdx.x * (NN / SSBLK);
    float accx[NSRC], accy[NSRC];
#pragma unroll
    for (int s = 0; s < NSRC; s++) { accx[s] = 0.f; accy[s] = 0.f; }

    __shared__ int cacc[NSRC];
    if (tid < NSRC) cacc[tid] = 0;
    __syncthreads();
    if (tid < (NN / SSBLK)) atomicAdd(&cacc[labels[row0 + tid]], 1);

#pragma unroll 4
    for (int j = 0; j < NN / SSBLK; j++) {
        const int lab = labels[row0 + j];
        const float2 v = *(const float2*)(txt + (size_t)(row0 + j) * DD + d0);
#pragma unroll
        for (int s = 0; s < NSRC; s++) {
            accx[s] += (lab == s) ? v.x : 0.f;
            accy[s] += (lab == s) ? v.y : 0.f;
        }
    }
    float* tp = Tpart + (size_t)blockIdx.x * (NSRC * DD);
#pragma unroll
    for (int s = 0; s < NSRC; s++) {
        float2 v; v.x = accx[s]; v.y = accy[s];
        *(float2*)(tp + s * DD + d0) = v;
    }
    __syncthreads();
    if (tid < NSRC) atomicAdd(&counts[tid], cacc[tid]);
}

// ---------------------------------------------------------------------------
// Kernel 1b: reduce partials -> Tsum. 16 blocks x 256 threads, 1 entry each;
// lane-consecutive entries -> every strided load is wave-coalesced.
// ---------------------------------------------------------------------------
__global__ __launch_bounds__(256) void k_src_reduce(
    const float* __restrict__ Tpart, float* __restrict__ Tsum)
{
    const int e = blockIdx.x * 256 + threadIdx.x;   // 4096 entries
    float sum = 0.f;
#pragma unroll 8
    for (int b = 0; b < SSBLK; b++)
        sum += Tpart[(size_t)b * (NSRC * DD) + e];
    Tsum[e] = sum;
}

// ---------------------------------------------------------------------------
// Kernel 2: MFMA flash-lse, 32x32x16 bf16, fixed-offset expsum (R4-proven).
// NEW: diagonal blocks (split == by>>2, ct == by&3) extract the raw diag dot
// img_i . txt_i from acc and store to dsbuf — finalize no longer recomputes.
// Lane algebra: diag element of row row0+w*32+lo sits at j==w,
// rg=(lo&3)+4*(lo>>3), on lanes with hi==(lo>>2)&1.
// ---------------------------------------------------------------------------
__global__ __launch_bounds__(256, 4) void k_lse_mfma(
    const unsigned short* __restrict__ imgB, const unsigned short* __restrict__ txtB,
    const float* __restrict__ scale_p,
    float* __restrict__ ps, float* __restrict__ dsbuf)
{
    __shared__ uint4 lds[2048];            // A: [0,1024), B: [1024,2048) chunks
    const float scale = scale_p[0];
    const int tid  = threadIdx.x;
    const int lane = tid & 63;
    const int w    = tid >> 6;             // wave id
    const int split = blockIdx.x & (SPLITS - 1);
    const int by    = blockIdx.x / SPLITS;
    const int row0  = by * BM;
    const int colBase = split * CPS;
    const int lo = lane & 31;              // row/col within 32-tile
    const int hi = lane >> 5;              // k-half selector
    const bool diagBlk = (split == (by >> 2));
    const int  diagCt  = by & 3;

    // staging geometry: thread stages physical chunk p = t*256 + tid
    int st_r[4], st_kc[4];
#pragma unroll
    for (int t = 0; t < 4; t++) {
        const int p = t * 256 + tid;
        st_r[t]  = p >> 3;
        st_kc[t] = (p & 7) ^ (st_r[t] & 7);
    }

    // fragment read bases (uint4 chunk indices)
    const int ar = w * 32 + lo;            // A row for this lane
    const int aIdx = ar * 8, aSw = ar & 7;
    int bIdx[4], bSw[4];
#pragma unroll
    for (int j = 0; j < 4; j++) {
        const int c = j * 32 + lo;         // B col for this lane
        bIdx[j] = 1024 + c * 8; bSw[j] = c & 7;
    }

    float s_run[16];
#pragma unroll
    for (int rg = 0; rg < 16; rg++) s_run[rg] = 0.f;

    for (int ct = 0; ct < CTILES; ct++) {
        const int col0 = colBase + ct * BN;
        f32x16 acc[4];
#pragma unroll
        for (int j = 0; j < 4; j++)
#pragma unroll
            for (int rg = 0; rg < 16; rg++) acc[j][rg] = 0.f;

        for (int kt = 0; kt < DD; kt += BK) {
            __syncthreads();               // previous tile's LDS reads done
#pragma unroll
            for (int t = 0; t < 4; t++) {  // stage A (128 rows x 64 k)
                const unsigned short* g =
                    imgB + (size_t)(row0 + st_r[t]) * DD + kt + (st_kc[t] << 3);
                __builtin_amdgcn_global_load_lds(
                    (const __attribute__((address_space(1))) void*)g,
                    (__attribute__((address_space(3))) void*)&lds[t * 256 + (w << 6)],
                    16, 0, 0);
            }
#pragma unroll
            for (int t = 0; t < 4; t++) {  // stage B (128 cols x 64 k)
                const unsigned short* g =
                    txtB + (size_t)(col0 + st_r[t]) * DD + kt + (st_kc[t] << 3);
                __builtin_amdgcn_global_load_lds(
                    (const __attribute__((address_space(1))) void*)g,
                    (__attribute__((address_space(3))) void*)&lds[1024 + t * 256 + (w << 6)],
                    16, 0, 0);
            }
            __syncthreads();               // drain global_load_lds
#pragma unroll
            for (int ks = 0; ks < 4; ks++) {   // 4 k-steps of 16
                const int kc = ks * 2 + hi;    // lane's k-chunk within BK
                const bf16x8 af = *reinterpret_cast<const bf16x8*>(
                    &lds[aIdx + (kc ^ aSw)]);
                bf16x8 bf[4];
#pragma unroll
                for (int j = 0; j < 4; j++)
                    bf[j] = *reinterpret_cast<const bf16x8*>(
                        &lds[bIdx[j] + (kc ^ bSw[j])]);
#pragma unroll
                for (int j = 0; j < 4; j++)
                    acc[j] = __builtin_amdgcn_mfma_f32_32x32x16_bf16(
                        af, bf[j], acc[j], 0, 0, 0);
            }
        }
        // diagonal extraction (raw dot, pre-scale) — 64 of 4096 block-cts
        if (diagBlk && ct == diagCt) {
            const int myrg = (lo & 3) + 4 * (lo >> 3);
            const bool mine = (hi == ((lo >> 2) & 1));
#pragma unroll
            for (int j = 0; j < 4; j++) if (j == w) {
                float dval = 0.f;
#pragma unroll
                for (int rg = 0; rg < 16; rg++)
                    dval = (rg == myrg) ? acc[j][rg] : dval;
                if (mine) dsbuf[row0 + w * 32 + lo] = dval;
            }
        }
        // epilogue: exp(logit - COFF), per-lane accumulation only
#pragma unroll
        for (int j = 0; j < 4; j++)
#pragma unroll
        for (int rg = 0; rg < 16; rg++)
            s_run[rg] += __expf(fmaf(acc[j][rg], scale, -COFF));
    }
    // reduce over the 32 col-lanes (xor offsets stay within the 32-group)
#pragma unroll
    for (int rg = 0; rg < 16; rg++) {
        float es = s_run[rg];
#pragma unroll
        for (int off = 16; off; off >>= 1) es += __shfl_xor(es, off);
        s_run[rg] = es;
    }
    if (lo == 0) {
#pragma unroll
        for (int rg = 0; rg < 16; rg++) {
            const int row = row0 + w * 32 + (rg & 3) + 8 * (rg >> 2) + 4 * hi;
            atomicAdd(&ps[row], s_run[rg]);
        }
    }
}

// ---------------------------------------------------------------------------
// Kernel 3: lse from ps, ds from dsbuf, dt = img_i . T_{lab_i}, loss reduce.
// 512 blocks x 4 waves x 4 rows. Only img re-read (txt no longer needed).
// ---------------------------------------------------------------------------
__global__ __launch_bounds__(256) void k_finalize(
    const float* __restrict__ img,
    const int* __restrict__ labels, const float* __restrict__ scale_p,
    const float* __restrict__ Tsum, const int* __restrict__ counts,
    const float* __restrict__ ps, const float* __restrict__ dsbuf,
    float* __restrict__ out)
{
    const float scale = scale_p[0];
    const int tid = threadIdx.x;
    const int lane = tid & 63;
    const int wave = tid >> 6;
    const int rowBase = blockIdx.x * 16 + wave * 4;
    float local = 0.f;
#pragma unroll
    for (int it = 0; it < 4; it++) {
        const int i = rowBase + it;
        const int lab = labels[i];
        float dt = 0.f;
        const float* ip = img + (size_t)i * DD;
        const float* sp = Tsum + lab * DD;
#pragma unroll
        for (int k = lane; k < DD; k += 64)
            dt = fmaf(ip[k], sp[k], dt);
#pragma unroll
        for (int off = 32; off; off >>= 1) dt += __shfl_xor(dt, off);
        if (lane == 0) {
            const float lse = COFF + __logf(ps[i]);
            const int cnt = counts[lab] - 1;
            if (cnt > 0) {
                const float row_sum = scale * (dt - dsbuf[i]) - (float)cnt * lse;
                local += row_sum / (float)cnt;
            }
        }
    }
    __shared__ float red[4];
    if (lane == 0) red[wave] = local;
    __syncthreads();
    if (tid == 0) {
        const float t = red[0] + red[1] + red[2] + red[3];
        atomicAdd(out, -t / (float)NN);
    }
}

// ---------------------------------------------------------------------------
extern "C" void kernel_launch(void* const* d_in, const int* in_sizes, int n_in,
                              void* d_out, int out_size, void* d_ws, size_t ws_size,
                              hipStream_t stream)
{
    const float* img     = (const float*)d_in[0];
    const float* txt     = (const float*)d_in[1];
    const float* scale_p = (const float*)d_in[2];
    const int*   labels  = (const int*)d_in[3];
    float* out = (float*)d_out;

    char* ws = (char*)d_ws;
    float* ps     = (float*)(ws);                        // 32 KB
    float* dsbuf  = (float*)(ws + 32 * 1024);            // 32 KB
    float* Tsum   = (float*)(ws + 64 * 1024);            // 16 KB
    int*   counts = (int*)(ws + 80 * 1024);              // 32 B
    unsigned short* imgB = (unsigned short*)(ws + 2 * 1024 * 1024);   // 8 MB
    unsigned short* txtB = (unsigned short*)(ws + 10 * 1024 * 1024);  // 8 MB
    float* Tpart  = (float*)(ws + 18 * 1024 * 1024);     // 2 MB

    k_cast<<<(2 * NN * DD / 8) / 256, 256, 0, stream>>>(img, txt, imgB, txtB,
                                                        ps, counts, out);
    k_src_sums<<<SSBLK, 256, 0, stream>>>(txt, labels, Tpart, counts);
    k_src_reduce<<<NSRC * DD / 256, 256, 0, stream>>>(Tpart, Tsum);
    k_lse_mfma<<<(NN / BM) * SPLITS, 256, 0, stream>>>(imgB, txtB, scale_p,
                                                       ps, dsbuf);
    k_finalize<<<NN / 16, 256, 0, stream>>>(img, labels, scale_p,
                                            Tsum, counts, ps, dsbuf, out);
}